// Round 5
// baseline (848.593 us; speedup 1.0000x reference)
//
#include <hip/hip_runtime.h>

#define DEV __device__ __forceinline__

typedef __bf16 bf16x8 __attribute__((ext_vector_type(8)));
typedef float f32x4 __attribute__((ext_vector_type(4)));
typedef unsigned short ushort8 __attribute__((ext_vector_type(8)));

constexpr int BATCH = 8192;
constexpr int HD    = 2048;                    // per-gate width = per-source K
constexpr size_t NX   = (size_t)BATCH * HD;    // x / h element count
constexpr size_t NW   = (size_t)HD * HD;       // one weight matrix
constexpr size_t NTOT = 2 * NX + 6 * NW;       // 58,720,256 elements

DEV unsigned short f2bf(float f) {
    unsigned int v = __builtin_bit_cast(unsigned int, f);
    unsigned int r = (v + 0x7FFFu + ((v >> 16) & 1u)) >> 16;  // RNE
    return (unsigned short)r;
}
DEV float sigm(float v)  { return 1.0f / (1.0f + __expf(-v)); }
DEV float tanh_(float v) {
    float z = fminf(fmaxf(v, -15.0f), 15.0f);
    float e = __expf(2.0f * z);
    return (e - 1.0f) / (e + 1.0f);
}

// async 16B/lane global->LDS; LDS base wave-uniform, lane l lands at base+l*16.
DEV void gl16(const unsigned short* g, unsigned short* lds_uniform_base) {
    __builtin_amdgcn_global_load_lds(
        (const __attribute__((address_space(1))) unsigned int*)g,
        (__attribute__((address_space(3))) unsigned int*)lds_uniform_base,
        16, 0, 0);
}

// ---------------- phase 1: f32 -> bf16 conversion into d_ws ----------------
// Layout in ws (ushort): [ x | h | Wix | Wmx | Wox | Wih | Wmh | Woh ]
// Segment select via uniform compile-time-constant compares: NO local array,
// NO dynamic kernarg indexing (rule #20: those go to scratch -> ~0.8 GB of
// scratch traffic across 7.3M threads).
__global__ __launch_bounds__(256) void cvt_all(
    const float* __restrict__ x,  const float* __restrict__ h,
    const float* __restrict__ w0, const float* __restrict__ w1,
    const float* __restrict__ w2, const float* __restrict__ w3,
    const float* __restrict__ w4, const float* __restrict__ w5,
    unsigned short* __restrict__ dst)
{
    const size_t base = (size_t)blockIdx.x * 2048;   // all seg bounds % 2048 == 0
    const float* src; size_t rel;
    if      (base <  NX)          { src = x;  rel = base; }
    else if (base < 2*NX)         { src = h;  rel = base - NX; }
    else if (base < 2*NX +   NW)  { src = w0; rel = base - 2*NX; }
    else if (base < 2*NX + 2*NW)  { src = w1; rel = base - (2*NX +   NW); }
    else if (base < 2*NX + 3*NW)  { src = w2; rel = base - (2*NX + 2*NW); }
    else if (base < 2*NX + 4*NW)  { src = w3; rel = base - (2*NX + 3*NW); }
    else if (base < 2*NX + 5*NW)  { src = w4; rel = base - (2*NX + 4*NW); }
    else                          { src = w5; rel = base - (2*NX + 5*NW); }
    const float* s = src + rel + threadIdx.x * 8;
    f32x4 u0 = *reinterpret_cast<const f32x4*>(s);
    f32x4 u1 = *reinterpret_cast<const f32x4*>(s + 4);
    ushort8 v;
#pragma unroll
    for (int j = 0; j < 4; ++j) { v[j] = f2bf(u0[j]); v[4 + j] = f2bf(u1[j]); }
    *reinterpret_cast<ushort8*>(dst + base + threadIdx.x * 8) = v;
}

// ---------------- phase 2: fused 3-gate GEMM + LSTM epilogue ---------------
// Block tile: 128 batch x 128 gate-cols x 3 gates, BK=32, 4 waves.
// Double-buffered LDS: issue global_load_lds for tile t+1 BEFORE computing
// tile t; the vmcnt(0) drain at the barrier then lands AFTER 48 MFMAs of
// cover instead of immediately after issue (T3 "minimum 2-phase" recipe).
__global__ __launch_bounds__(256, 2) void lstm_fast(
    const unsigned short* __restrict__ xb, const unsigned short* __restrict__ hb,
    const unsigned short* __restrict__ W0x, const unsigned short* __restrict__ W1x,
    const unsigned short* __restrict__ W2x, const unsigned short* __restrict__ W0h,
    const unsigned short* __restrict__ W1h, const unsigned short* __restrict__ W2h,
    const float* __restrict__ c,
    const float* __restrict__ bix, const float* __restrict__ bih,
    const float* __restrict__ bmx, const float* __restrict__ bmh,
    const float* __restrict__ box_, const float* __restrict__ boh,
    float* __restrict__ hout, float* __restrict__ cout)
{
    __shared__ unsigned short As [2][128 * 32];
    __shared__ unsigned short B0s[2][128 * 32];
    __shared__ unsigned short B1s[2][128 * 32];
    __shared__ unsigned short B2s[2][128 * 32];

    const int tid  = threadIdx.x;
    const int lane = tid & 63;
    const int wave = tid >> 6;

    const int n0 = blockIdx.x * 128;   // gate-col tile (0..15)
    const int m0 = blockIdx.y * 128;   // batch tile   (0..63)

    const int arow = lane >> 2;        // staging: 16 rows / gl16
    const int acol = (lane & 3) * 8;   // 4 lanes/row, 16B each

    const int mOff = (wave >> 1) * 64;
    const int nOff = (wave & 1) * 64;
    const int q    = lane >> 4;
    const int ml   = lane & 15;

    const int r0 = wave * 32, r1 = wave * 32 + 16;

    // loop-invariant staging offsets (only kk varies per K-step)
    const size_t aoff0 = (size_t)(m0 + r0 + arow) * HD + acol;
    const size_t aoff1 = (size_t)(m0 + r1 + arow) * HD + acol;
    const size_t boff0 = (size_t)(n0 + r0 + arow) * HD + acol;
    const size_t boff1 = (size_t)(n0 + r1 + arow) * HD + acol;

    f32x4 a0[4][4] = {};   // gate i
    f32x4 a1[4][4] = {};   // gate m
    f32x4 a2[4][4] = {};   // gate o

    auto stage = [&](int kt, int buf) {
        const int k0 = kt * 32;
        const unsigned short *Asrc, *W0, *W1, *W2;
        int kk;
        if (k0 < HD) { Asrc = xb; W0 = W0x; W1 = W1x; W2 = W2x; kk = k0; }
        else         { Asrc = hb; W0 = W0h; W1 = W1h; W2 = W2h; kk = k0 - HD; }
        gl16(Asrc + aoff0 + kk, &As [buf][r0 * 32]);
        gl16(Asrc + aoff1 + kk, &As [buf][r1 * 32]);
        gl16(W0   + boff0 + kk, &B0s[buf][r0 * 32]);
        gl16(W0   + boff1 + kk, &B0s[buf][r1 * 32]);
        gl16(W1   + boff0 + kk, &B1s[buf][r0 * 32]);
        gl16(W1   + boff1 + kk, &B1s[buf][r1 * 32]);
        gl16(W2   + boff0 + kk, &B2s[buf][r0 * 32]);
        gl16(W2   + boff1 + kk, &B2s[buf][r1 * 32]);
    };

    auto compute = [&](int buf) {
        bf16x8 af[4];
#pragma unroll
        for (int t = 0; t < 4; ++t)
            af[t] = *reinterpret_cast<const bf16x8*>(&As[buf][(mOff + t * 16 + ml) * 32 + q * 8]);
        {
            bf16x8 bfr[4];
#pragma unroll
            for (int tn = 0; tn < 4; ++tn)
                bfr[tn] = *reinterpret_cast<const bf16x8*>(&B0s[buf][(nOff + tn * 16 + ml) * 32 + q * 8]);
#pragma unroll
            for (int tm = 0; tm < 4; ++tm)
#pragma unroll
                for (int tn = 0; tn < 4; ++tn)
                    a0[tm][tn] = __builtin_amdgcn_mfma_f32_16x16x32_bf16(af[tm], bfr[tn], a0[tm][tn], 0, 0, 0);
        }
        {
            bf16x8 bfr[4];
#pragma unroll
            for (int tn = 0; tn < 4; ++tn)
                bfr[tn] = *reinterpret_cast<const bf16x8*>(&B1s[buf][(nOff + tn * 16 + ml) * 32 + q * 8]);
#pragma unroll
            for (int tm = 0; tm < 4; ++tm)
#pragma unroll
                for (int tn = 0; tn < 4; ++tn)
                    a1[tm][tn] = __builtin_amdgcn_mfma_f32_16x16x32_bf16(af[tm], bfr[tn], a1[tm][tn], 0, 0, 0);
        }
        {
            bf16x8 bfr[4];
#pragma unroll
            for (int tn = 0; tn < 4; ++tn)
                bfr[tn] = *reinterpret_cast<const bf16x8*>(&B2s[buf][(nOff + tn * 16 + ml) * 32 + q * 8]);
#pragma unroll
            for (int tm = 0; tm < 4; ++tm)
#pragma unroll
                for (int tn = 0; tn < 4; ++tn)
                    a2[tm][tn] = __builtin_amdgcn_mfma_f32_16x16x32_bf16(af[tm], bfr[tn], a2[tm][tn], 0, 0, 0);
        }
    };

    // prologue: stage tile 0, drain, barrier
    stage(0, 0);
    asm volatile("s_waitcnt vmcnt(0)" ::: "memory");
    __syncthreads();

    int cur = 0;
    for (int kt = 0; kt < 127; ++kt) {
        stage(kt + 1, cur ^ 1);   // issue next-tile loads (in flight during MFMA)
        compute(cur);
        asm volatile("s_waitcnt vmcnt(0)" ::: "memory");
        __syncthreads();          // next tile ready; all reads of cur done
        cur ^= 1;
    }
    compute(cur);                 // tile 127, no prefetch

    // LSTM epilogue; C/D map (m89-verified): col = lane&15, row = (lane>>4)*4+reg
#pragma unroll
    for (int tn = 0; tn < 4; ++tn) {
        const int col = n0 + nOff + tn * 16 + ml;      // 0..2047
        const float Bi = bix[col] + bih[col];
        const float Bm = bmx[col] + bmh[col];
        const float Bo = box_[col] + boh[col];
#pragma unroll
        for (int tm = 0; tm < 4; ++tm) {
            const int rb = m0 + mOff + tm * 16 + q * 4;
#pragma unroll
            for (int r = 0; r < 4; ++r) {
                const size_t b = rb + r;
                const float cold = c[b * HD + col];
                const float gi = a0[tm][tn][r] + Bi;
                const float gm = a1[tm][tn][r] + Bm;
                const float go = a2[tm][tn][r] + Bo;
                const float i_s = sigm(gi);
                const float f_s = sigm(gm);    // reference quirk: gm drives both
                const float m_s = tanh_(gm);   // forget-sigmoid and candidate-tanh
                const float o_s = sigm(go);
                const float cn  = f_s * cold + i_s * m_s;
                const float hn  = o_s * tanh_(cn);
                hout[b * HD + col] = hn;
                cout[b * HD + col] = cn;
            }
        }
    }
}

// ---------------- fallback (R3-proven, f32 in, no ws) ----------------------
DEV void stage64f(unsigned short* lds, const float* src, size_t row_base, int kk, int tid) {
    const int r  = tid >> 2;
    const int cc = (tid & 3) * 8;
    const float* s = src + (row_base + r) * (size_t)HD + kk + cc;
    f32x4 u0 = *(const f32x4*)s;
    f32x4 u1 = *(const f32x4*)(s + 4);
    ushort8 v;
#pragma unroll
    for (int j = 0; j < 4; ++j) { v[j] = f2bf(u0[j]); v[4 + j] = f2bf(u1[j]); }
    *reinterpret_cast<ushort8*>(&lds[r * 32 + cc]) = v;
}

__global__ __launch_bounds__(256, 2) void lstm_slow(
    const float* __restrict__ x,   const float* __restrict__ h,
    const float* __restrict__ c,
    const float* __restrict__ Wix, const float* __restrict__ bix,
    const float* __restrict__ Wmx, const float* __restrict__ bmx,
    const float* __restrict__ Wox, const float* __restrict__ box_,
    const float* __restrict__ Wih, const float* __restrict__ bih,
    const float* __restrict__ Wmh, const float* __restrict__ bmh,
    const float* __restrict__ Woh, const float* __restrict__ boh,
    float* __restrict__ hout, float* __restrict__ cout)
{
    __shared__ unsigned short As[64 * 32];
    __shared__ unsigned short B0s[128 * 32];
    __shared__ unsigned short B1s[128 * 32];
    __shared__ unsigned short B2s[128 * 32];

    const int tid  = threadIdx.x;
    const int lane = tid & 63;
    const int wave = tid >> 6;
    const int n0 = blockIdx.x * 128;
    const int m0 = blockIdx.y * 64;
    const int mOff = (wave >> 1) * 32;
    const int nOff = (wave & 1) * 64;
    const int q    = lane >> 4;
    const int ml   = lane & 15;

    f32x4 a0[2][4] = {}; f32x4 a1[2][4] = {}; f32x4 a2[2][4] = {};

    auto kstep = [&](const float* Asrc, const float* W0, const float* W1,
                     const float* W2, int kk) {
        stage64f(As, Asrc, m0, kk, tid & 255);
        stage64f(B0s,           W0, n0,      kk, tid);
        stage64f(B0s + 64 * 32, W0, n0 + 64, kk, tid);
        stage64f(B1s,           W1, n0,      kk, tid);
        stage64f(B1s + 64 * 32, W1, n0 + 64, kk, tid);
        stage64f(B2s,           W2, n0,      kk, tid);
        stage64f(B2s + 64 * 32, W2, n0 + 64, kk, tid);
        __syncthreads();
        bf16x8 af[2], bfr[4];
        af[0] = *reinterpret_cast<const bf16x8*>(&As[(mOff      + ml) * 32 + q * 8]);
        af[1] = *reinterpret_cast<const bf16x8*>(&As[(mOff + 16 + ml) * 32 + q * 8]);
#pragma unroll
        for (int tn = 0; tn < 4; ++tn)
            bfr[tn] = *reinterpret_cast<const bf16x8*>(&B0s[(nOff + tn * 16 + ml) * 32 + q * 8]);
#pragma unroll
        for (int tm = 0; tm < 2; ++tm)
#pragma unroll
            for (int tn = 0; tn < 4; ++tn)
                a0[tm][tn] = __builtin_amdgcn_mfma_f32_16x16x32_bf16(af[tm], bfr[tn], a0[tm][tn], 0, 0, 0);
#pragma unroll
        for (int tn = 0; tn < 4; ++tn)
            bfr[tn] = *reinterpret_cast<const bf16x8*>(&B1s[(nOff + tn * 16 + ml) * 32 + q * 8]);
#pragma unroll
        for (int tm = 0; tm < 2; ++tm)
#pragma unroll
            for (int tn = 0; tn < 4; ++tn)
                a1[tm][tn] = __builtin_amdgcn_mfma_f32_16x16x32_bf16(af[tm], bfr[tn], a1[tm][tn], 0, 0, 0);
#pragma unroll
        for (int tn = 0; tn < 4; ++tn)
            bfr[tn] = *reinterpret_cast<const bf16x8*>(&B2s[(nOff + tn * 16 + ml) * 32 + q * 8]);
#pragma unroll
        for (int tm = 0; tm < 2; ++tm)
#pragma unroll
            for (int tn = 0; tn < 4; ++tn)
                a2[tm][tn] = __builtin_amdgcn_mfma_f32_16x16x32_bf16(af[tm], bfr[tn], a2[tm][tn], 0, 0, 0);
        __syncthreads();
    };

    for (int kt = 0; kt < 64; ++kt) kstep(x, Wix, Wmx, Wox, kt * 32);
    for (int kt = 0; kt < 64; ++kt) kstep(h, Wih, Wmh, Woh, kt * 32);

#pragma unroll
    for (int tn = 0; tn < 4; ++tn) {
        const int col = n0 + nOff + tn * 16 + ml;
        const float Bi = bix[col] + bih[col];
        const float Bm = bmx[col] + bmh[col];
        const float Bo = box_[col] + boh[col];
#pragma unroll
        for (int tm = 0; tm < 2; ++tm) {
            const int rb = m0 + mOff + tm * 16 + q * 4;
#pragma unroll
            for (int r = 0; r < 4; ++r) {
                const size_t b = rb + r;
                const float cold = c[b * HD + col];
                const float gi = a0[tm][tn][r] + Bi;
                const float gm = a1[tm][tn][r] + Bm;
                const float go = a2[tm][tn][r] + Bo;
                const float cn = sigm(gm) * cold + sigm(gi) * tanh_(gm);
                const float hn = sigm(go) * tanh_(cn);
                hout[b * HD + col] = hn;
                cout[b * HD + col] = cn;
            }
        }
    }
}

// ----------------------------------------------------------------------------
extern "C" void kernel_launch(void* const* d_in, const int* in_sizes, int n_in,
                              void* d_out, int out_size, void* d_ws, size_t ws_size,
                              hipStream_t stream) {
    const float* x   = (const float*)d_in[0];
    const float* h   = (const float*)d_in[1];
    const float* c   = (const float*)d_in[2];
    const float* Wix = (const float*)d_in[3];  const float* bix = (const float*)d_in[4];
    const float* Wmx = (const float*)d_in[5];  const float* bmx = (const float*)d_in[6];
    const float* Wox = (const float*)d_in[7];  const float* box_= (const float*)d_in[8];
    const float* Wih = (const float*)d_in[9];  const float* bih = (const float*)d_in[10];
    const float* Wmh = (const float*)d_in[11]; const float* bmh = (const float*)d_in[12];
    const float* Woh = (const float*)d_in[13]; const float* boh = (const float*)d_in[14];

    float* hout = (float*)d_out;
    float* cout = hout + NX;

    if (ws_size >= NTOT * sizeof(unsigned short)) {
        unsigned short* ws = (unsigned short*)d_ws;
        cvt_all<<<dim3((unsigned)(NTOT / 2048)), dim3(256), 0, stream>>>(
            x, h, Wix, Wmx, Wox, Wih, Wmh, Woh, ws);

        const unsigned short* xb  = ws;
        const unsigned short* hb  = ws + NX;
        const unsigned short* W0x = ws + 2 * NX;           // Wix
        const unsigned short* W1x = ws + 2 * NX + NW;      // Wmx
        const unsigned short* W2x = ws + 2 * NX + 2 * NW;  // Wox
        const unsigned short* W0h = ws + 2 * NX + 3 * NW;  // Wih
        const unsigned short* W1h = ws + 2 * NX + 4 * NW;  // Wmh
        const unsigned short* W2h = ws + 2 * NX + 5 * NW;  // Woh

        lstm_fast<<<dim3(HD / 128, BATCH / 128), dim3(256), 0, stream>>>(
            xb, hb, W0x, W1x, W2x, W0h, W1h, W2h,
            c, bix, bih, bmx, bmh, box_, boh, hout, cout);
    } else {
        lstm_slow<<<dim3(HD / 128, BATCH / 64), dim3(256), 0, stream>>>(
            x, h, c, Wix, bix, Wmx, bmx, Wox, box_,
            Wih, bih, Wmh, bmh, Woh, boh, hout, cout);
    }
}

// Round 6
// 793.805 us; speedup vs baseline: 1.0690x; 1.0690x over previous
//
#include <hip/hip_runtime.h>

#define DEV __device__ __forceinline__

typedef __bf16 bf16x8 __attribute__((ext_vector_type(8)));
typedef float f32x4 __attribute__((ext_vector_type(4)));
typedef unsigned short ushort8 __attribute__((ext_vector_type(8)));

constexpr int BATCH = 8192;
constexpr int HD    = 2048;                    // per-gate width = per-source K
constexpr size_t NX   = (size_t)BATCH * HD;    // x / h element count
constexpr size_t NW   = (size_t)HD * HD;       // one weight matrix
constexpr size_t NTOT = 2 * NX + 6 * NW;       // 58,720,256 elements

DEV unsigned short f2bf(float f) {
    unsigned int v = __builtin_bit_cast(unsigned int, f);
    unsigned int r = (v + 0x7FFFu + ((v >> 16) & 1u)) >> 16;  // RNE
    return (unsigned short)r;
}
DEV float sigm(float v)  { return 1.0f / (1.0f + __expf(-v)); }
DEV float tanh_(float v) {
    float z = fminf(fmaxf(v, -15.0f), 15.0f);
    float e = __expf(2.0f * z);
    return (e - 1.0f) / (e + 1.0f);
}

// async 16B/lane global->LDS; LDS base wave-uniform, lane l lands at base+l*16.
DEV void gl16(const unsigned short* g, unsigned short* lds_uniform_base) {
    __builtin_amdgcn_global_load_lds(
        (const __attribute__((address_space(1))) unsigned int*)g,
        (__attribute__((address_space(3))) unsigned int*)lds_uniform_base,
        16, 0, 0);
}

// ---------------- phase 1: f32 -> bf16 conversion into d_ws ----------------
// Layout in ws (ushort): [ x | h | Wix | Wmx | Wox | Wih | Wmh | Woh ]
__global__ __launch_bounds__(256) void cvt_all(
    const float* __restrict__ x,  const float* __restrict__ h,
    const float* __restrict__ w0, const float* __restrict__ w1,
    const float* __restrict__ w2, const float* __restrict__ w3,
    const float* __restrict__ w4, const float* __restrict__ w5,
    unsigned short* __restrict__ dst)
{
    const size_t base = (size_t)blockIdx.x * 2048;   // all seg bounds % 2048 == 0
    const float* src; size_t rel;
    if      (base <  NX)          { src = x;  rel = base; }
    else if (base < 2*NX)         { src = h;  rel = base - NX; }
    else if (base < 2*NX +   NW)  { src = w0; rel = base - 2*NX; }
    else if (base < 2*NX + 2*NW)  { src = w1; rel = base - (2*NX +   NW); }
    else if (base < 2*NX + 3*NW)  { src = w2; rel = base - (2*NX + 2*NW); }
    else if (base < 2*NX + 4*NW)  { src = w3; rel = base - (2*NX + 3*NW); }
    else if (base < 2*NX + 5*NW)  { src = w4; rel = base - (2*NX + 4*NW); }
    else                          { src = w5; rel = base - (2*NX + 5*NW); }
    const float* s = src + rel + threadIdx.x * 8;
    f32x4 u0 = *reinterpret_cast<const f32x4*>(s);
    f32x4 u1 = *reinterpret_cast<const f32x4*>(s + 4);
    ushort8 v;
#pragma unroll
    for (int j = 0; j < 4; ++j) { v[j] = f2bf(u0[j]); v[4 + j] = f2bf(u1[j]); }
    *reinterpret_cast<ushort8*>(dst + base + threadIdx.x * 8) = v;
}

// ---------------- phase 2: fused 3-gate GEMM + LSTM epilogue ---------------
// Block tile: 128 batch x 128 gate-cols x 3 gates, BK=32, 4 waves.
// T4 counted-vmcnt pipeline (2-deep): raw s_barrier (NO __syncthreads -> no
// compiler-forced vmcnt(0) drain); per K-step the wave keeps the NEXT tile's
// 8 global_load_lds in flight across the barrier and waits only vmcnt(8).
// Static buffer indices via 2-step manual unroll (no runtime LDS base adds).
__global__ __launch_bounds__(256, 2) void lstm_fast(
    const unsigned short* __restrict__ xb, const unsigned short* __restrict__ hb,
    const unsigned short* __restrict__ W0x, const unsigned short* __restrict__ W1x,
    const unsigned short* __restrict__ W2x, const unsigned short* __restrict__ W0h,
    const unsigned short* __restrict__ W1h, const unsigned short* __restrict__ W2h,
    const float* __restrict__ c,
    const float* __restrict__ bix, const float* __restrict__ bih,
    const float* __restrict__ bmx, const float* __restrict__ bmh,
    const float* __restrict__ box_, const float* __restrict__ boh,
    float* __restrict__ hout, float* __restrict__ cout)
{
    __shared__ unsigned short As [2][128 * 32];
    __shared__ unsigned short B0s[2][128 * 32];
    __shared__ unsigned short B1s[2][128 * 32];
    __shared__ unsigned short B2s[2][128 * 32];

    const int tid  = threadIdx.x;
    const int lane = tid & 63;
    const int wave = tid >> 6;

    const int n0 = blockIdx.x * 128;   // gate-col tile (0..15)
    const int m0 = blockIdx.y * 128;   // batch tile   (0..63)

    const int arow = lane >> 2;        // staging: 16 rows / gl16
    const int acol = (lane & 3) * 8;   // 4 lanes/row, 16B each

    const int mOff = (wave >> 1) * 64;
    const int nOff = (wave & 1) * 64;
    const int q    = lane >> 4;
    const int ml   = lane & 15;

    const int r0 = wave * 32, r1 = wave * 32 + 16;

    // loop-invariant staging offsets (only kk varies per K-step)
    const size_t aoff0 = (size_t)(m0 + r0 + arow) * HD + acol;
    const size_t aoff1 = (size_t)(m0 + r1 + arow) * HD + acol;
    const size_t boff0 = (size_t)(n0 + r0 + arow) * HD + acol;
    const size_t boff1 = (size_t)(n0 + r1 + arow) * HD + acol;

    f32x4 a0[4][4] = {};   // gate i
    f32x4 a1[4][4] = {};   // gate m
    f32x4 a2[4][4] = {};   // gate o

    auto stage = [&](int kt, int buf) {
        const int k0 = kt * 32;
        const unsigned short *Asrc, *W0, *W1, *W2;
        int kk;
        if (k0 < HD) { Asrc = xb; W0 = W0x; W1 = W1x; W2 = W2x; kk = k0; }
        else         { Asrc = hb; W0 = W0h; W1 = W1h; W2 = W2h; kk = k0 - HD; }
        gl16(Asrc + aoff0 + kk, &As [buf][r0 * 32]);
        gl16(Asrc + aoff1 + kk, &As [buf][r1 * 32]);
        gl16(W0   + boff0 + kk, &B0s[buf][r0 * 32]);
        gl16(W0   + boff1 + kk, &B0s[buf][r1 * 32]);
        gl16(W1   + boff0 + kk, &B1s[buf][r0 * 32]);
        gl16(W1   + boff1 + kk, &B1s[buf][r1 * 32]);
        gl16(W2   + boff0 + kk, &B2s[buf][r0 * 32]);
        gl16(W2   + boff1 + kk, &B2s[buf][r1 * 32]);
    };

    auto compute = [&](int buf) {
        bf16x8 af[4];
#pragma unroll
        for (int t = 0; t < 4; ++t)
            af[t] = *reinterpret_cast<const bf16x8*>(&As[buf][(mOff + t * 16 + ml) * 32 + q * 8]);
        {
            bf16x8 bfr[4];
#pragma unroll
            for (int tn = 0; tn < 4; ++tn)
                bfr[tn] = *reinterpret_cast<const bf16x8*>(&B0s[buf][(nOff + tn * 16 + ml) * 32 + q * 8]);
#pragma unroll
            for (int tm = 0; tm < 4; ++tm)
#pragma unroll
                for (int tn = 0; tn < 4; ++tn)
                    a0[tm][tn] = __builtin_amdgcn_mfma_f32_16x16x32_bf16(af[tm], bfr[tn], a0[tm][tn], 0, 0, 0);
        }
        {
            bf16x8 bfr[4];
#pragma unroll
            for (int tn = 0; tn < 4; ++tn)
                bfr[tn] = *reinterpret_cast<const bf16x8*>(&B1s[buf][(nOff + tn * 16 + ml) * 32 + q * 8]);
#pragma unroll
            for (int tm = 0; tm < 4; ++tm)
#pragma unroll
                for (int tn = 0; tn < 4; ++tn)
                    a1[tm][tn] = __builtin_amdgcn_mfma_f32_16x16x32_bf16(af[tm], bfr[tn], a1[tm][tn], 0, 0, 0);
        }
        {
            bf16x8 bfr[4];
#pragma unroll
            for (int tn = 0; tn < 4; ++tn)
                bfr[tn] = *reinterpret_cast<const bf16x8*>(&B2s[buf][(nOff + tn * 16 + ml) * 32 + q * 8]);
#pragma unroll
            for (int tm = 0; tm < 4; ++tm)
#pragma unroll
                for (int tn = 0; tn < 4; ++tn)
                    a2[tm][tn] = __builtin_amdgcn_mfma_f32_16x16x32_bf16(af[tm], bfr[tn], a2[tm][tn], 0, 0, 0);
        }
    };

    // prologue: stage tiles 0 and 1 (16 loads in flight), wait tile 0 only
    stage(0, 0);
    stage(1, 1);
    asm volatile("s_waitcnt vmcnt(8)" ::: "memory");
    __builtin_amdgcn_s_barrier();
    __builtin_amdgcn_sched_barrier(0);

    // steady state: invariant at each step head — tile kt ready in buf[kt&1],
    // tile kt+1's 8 loads in flight.
#pragma unroll 1
    for (int kt = 0; kt < 126; kt += 2) {
        // even step: tile kt in buf0
        compute(0);
        __builtin_amdgcn_s_barrier();                      // all reads of buf0 done
        stage(kt + 2, 0);                                  // overwrite buf0 (16 in flight)
        asm volatile("s_waitcnt vmcnt(8)" ::: "memory");   // tile kt+1 landed
        __builtin_amdgcn_s_barrier();                      // visible to all waves
        __builtin_amdgcn_sched_barrier(0);
        // odd step: tile kt+1 in buf1
        compute(1);
        __builtin_amdgcn_s_barrier();
        stage(kt + 3, 1);
        asm volatile("s_waitcnt vmcnt(8)" ::: "memory");   // tile kt+2 landed
        __builtin_amdgcn_s_barrier();
        __builtin_amdgcn_sched_barrier(0);
    }
    // kt == 126: tile 126 ready in buf0; tile 127's loads in flight
    compute(0);                                            // tile 126
    __builtin_amdgcn_s_barrier();
    asm volatile("s_waitcnt vmcnt(0)" ::: "memory");       // tile 127 landed
    __builtin_amdgcn_s_barrier();
    __builtin_amdgcn_sched_barrier(0);
    compute(1);                                            // tile 127

    // LSTM epilogue; C/D map (m89-verified): col = lane&15, row = (lane>>4)*4+reg
#pragma unroll
    for (int tn = 0; tn < 4; ++tn) {
        const int col = n0 + nOff + tn * 16 + ml;      // 0..2047
        const float Bi = bix[col] + bih[col];
        const float Bm = bmx[col] + bmh[col];
        const float Bo = box_[col] + boh[col];
#pragma unroll
        for (int tm = 0; tm < 4; ++tm) {
            const int rb = m0 + mOff + tm * 16 + q * 4;
#pragma unroll
            for (int r = 0; r < 4; ++r) {
                const size_t b = rb + r;
                const float cold = c[b * HD + col];
                const float gi = a0[tm][tn][r] + Bi;
                const float gm = a1[tm][tn][r] + Bm;
                const float go = a2[tm][tn][r] + Bo;
                const float i_s = sigm(gi);
                const float f_s = sigm(gm);    // reference quirk: gm drives both
                const float m_s = tanh_(gm);   // forget-sigmoid and candidate-tanh
                const float o_s = sigm(go);
                const float cn  = f_s * cold + i_s * m_s;
                const float hn  = o_s * tanh_(cn);
                hout[b * HD + col] = hn;
                cout[b * HD + col] = cn;
            }
        }
    }
}

// ---------------- fallback (R3-proven, f32 in, no ws) ----------------------
DEV void stage64f(unsigned short* lds, const float* src, size_t row_base, int kk, int tid) {
    const int r  = tid >> 2;
    const int cc = (tid & 3) * 8;
    const float* s = src + (row_base + r) * (size_t)HD + kk + cc;
    f32x4 u0 = *(const f32x4*)s;
    f32x4 u1 = *(const f32x4*)(s + 4);
    ushort8 v;
#pragma unroll
    for (int j = 0; j < 4; ++j) { v[j] = f2bf(u0[j]); v[4 + j] = f2bf(u1[j]); }
    *reinterpret_cast<ushort8*>(&lds[r * 32 + cc]) = v;
}

__global__ __launch_bounds__(256, 2) void lstm_slow(
    const float* __restrict__ x,   const float* __restrict__ h,
    const float* __restrict__ c,
    const float* __restrict__ Wix, const float* __restrict__ bix,
    const float* __restrict__ Wmx, const float* __restrict__ bmx,
    const float* __restrict__ Wox, const float* __restrict__ box_,
    const float* __restrict__ Wih, const float* __restrict__ bih,
    const float* __restrict__ Wmh, const float* __restrict__ bmh,
    const float* __restrict__ Woh, const float* __restrict__ boh,
    float* __restrict__ hout, float* __restrict__ cout)
{
    __shared__ unsigned short As[64 * 32];
    __shared__ unsigned short B0s[128 * 32];
    __shared__ unsigned short B1s[128 * 32];
    __shared__ unsigned short B2s[128 * 32];

    const int tid  = threadIdx.x;
    const int lane = tid & 63;
    const int wave = tid >> 6;
    const int n0 = blockIdx.x * 128;
    const int m0 = blockIdx.y * 64;
    const int mOff = (wave >> 1) * 32;
    const int nOff = (wave & 1) * 64;
    const int q    = lane >> 4;
    const int ml   = lane & 15;

    f32x4 a0[2][4] = {}; f32x4 a1[2][4] = {}; f32x4 a2[2][4] = {};

    auto kstep = [&](const float* Asrc, const float* W0, const float* W1,
                     const float* W2, int kk) {
        stage64f(As, Asrc, m0, kk, tid & 255);
        stage64f(B0s,           W0, n0,      kk, tid);
        stage64f(B0s + 64 * 32, W0, n0 + 64, kk, tid);
        stage64f(B1s,           W1, n0,      kk, tid);
        stage64f(B1s + 64 * 32, W1, n0 + 64, kk, tid);
        stage64f(B2s,           W2, n0,      kk, tid);
        stage64f(B2s + 64 * 32, W2, n0 + 64, kk, tid);
        __syncthreads();
        bf16x8 af[2], bfr[4];
        af[0] = *reinterpret_cast<const bf16x8*>(&As[(mOff      + ml) * 32 + q * 8]);
        af[1] = *reinterpret_cast<const bf16x8*>(&As[(mOff + 16 + ml) * 32 + q * 8]);
#pragma unroll
        for (int tn = 0; tn < 4; ++tn)
            bfr[tn] = *reinterpret_cast<const bf16x8*>(&B0s[(nOff + tn * 16 + ml) * 32 + q * 8]);
#pragma unroll
        for (int tm = 0; tm < 2; ++tm)
#pragma unroll
            for (int tn = 0; tn < 4; ++tn)
                a0[tm][tn] = __builtin_amdgcn_mfma_f32_16x16x32_bf16(af[tm], bfr[tn], a0[tm][tn], 0, 0, 0);
#pragma unroll
        for (int tn = 0; tn < 4; ++tn)
            bfr[tn] = *reinterpret_cast<const bf16x8*>(&B1s[(nOff + tn * 16 + ml) * 32 + q * 8]);
#pragma unroll
        for (int tm = 0; tm < 2; ++tm)
#pragma unroll
            for (int tn = 0; tn < 4; ++tn)
                a1[tm][tn] = __builtin_amdgcn_mfma_f32_16x16x32_bf16(af[tm], bfr[tn], a1[tm][tn], 0, 0, 0);
#pragma unroll
        for (int tn = 0; tn < 4; ++tn)
            bfr[tn] = *reinterpret_cast<const bf16x8*>(&B2s[(nOff + tn * 16 + ml) * 32 + q * 8]);
#pragma unroll
        for (int tm = 0; tm < 2; ++tm)
#pragma unroll
            for (int tn = 0; tn < 4; ++tn)
                a2[tm][tn] = __builtin_amdgcn_mfma_f32_16x16x32_bf16(af[tm], bfr[tn], a2[tm][tn], 0, 0, 0);
        __syncthreads();
    };

    for (int kt = 0; kt < 64; ++kt) kstep(x, Wix, Wmx, Wox, kt * 32);
    for (int kt = 0; kt < 64; ++kt) kstep(h, Wih, Wmh, Woh, kt * 32);

#pragma unroll
    for (int tn = 0; tn < 4; ++tn) {
        const int col = n0 + nOff + tn * 16 + ml;
        const float Bi = bix[col] + bih[col];
        const float Bm = bmx[col] + bmh[col];
        const float Bo = box_[col] + boh[col];
#pragma unroll
        for (int tm = 0; tm < 2; ++tm) {
            const int rb = m0 + mOff + tm * 16 + q * 4;
#pragma unroll
            for (int r = 0; r < 4; ++r) {
                const size_t b = rb + r;
                const float cold = c[b * HD + col];
                const float gi = a0[tm][tn][r] + Bi;
                const float gm = a1[tm][tn][r] + Bm;
                const float go = a2[tm][tn][r] + Bo;
                const float cn = sigm(gm) * cold + sigm(gi) * tanh_(gm);
                const float hn = sigm(go) * tanh_(cn);
                hout[b * HD + col] = hn;
                cout[b * HD + col] = cn;
            }
        }
    }
}

// ----------------------------------------------------------------------------
extern "C" void kernel_launch(void* const* d_in, const int* in_sizes, int n_in,
                              void* d_out, int out_size, void* d_ws, size_t ws_size,
                              hipStream_t stream) {
    const float* x   = (const float*)d_in[0];
    const float* h   = (const float*)d_in[1];
    const float* c   = (const float*)d_in[2];
    const float* Wix = (const float*)d_in[3];  const float* bix = (const float*)d_in[4];
    const float* Wmx = (const float*)d_in[5];  const float* bmx = (const float*)d_in[6];
    const float* Wox = (const float*)d_in[7];  const float* box_= (const float*)d_in[8];
    const float* Wih = (const float*)d_in[9];  const float* bih = (const float*)d_in[10];
    const float* Wmh = (const float*)d_in[11]; const float* bmh = (const float*)d_in[12];
    const float* Woh = (const float*)d_in[13]; const float* boh = (const float*)d_in[14];

    float* hout = (float*)d_out;
    float* cout = hout + NX;

    if (ws_size >= NTOT * sizeof(unsigned short)) {
        unsigned short* ws = (unsigned short*)d_ws;
        cvt_all<<<dim3((unsigned)(NTOT / 2048)), dim3(256), 0, stream>>>(
            x, h, Wix, Wmx, Wox, Wih, Wmh, Woh, ws);

        const unsigned short* xb  = ws;
        const unsigned short* hb  = ws + NX;
        const unsigned short* W0x = ws + 2 * NX;           // Wix
        const unsigned short* W1x = ws + 2 * NX + NW;      // Wmx
        const unsigned short* W2x = ws + 2 * NX + 2 * NW;  // Wox
        const unsigned short* W0h = ws + 2 * NX + 3 * NW;  // Wih
        const unsigned short* W1h = ws + 2 * NX + 4 * NW;  // Wmh
        const unsigned short* W2h = ws + 2 * NX + 5 * NW;  // Woh

        lstm_fast<<<dim3(HD / 128, BATCH / 128), dim3(256), 0, stream>>>(
            xb, hb, W0x, W1x, W2x, W0h, W1h, W2h,
            c, bix, bih, bmx, bmh, box_, boh, hout, cout);
    } else {
        lstm_slow<<<dim3(HD / 128, BATCH / 64), dim3(256), 0, stream>>>(
            x, h, c, Wix, bix, Wmx, bmx, Wox, box_,
            Wih, bih, Wmh, bmh, Woh, boh, hout, cout);
    }
}